// Round 5
// baseline (111.931 us; speedup 1.0000x reference)
//
#include <hip/hip_runtime.h>

// Chamfer distance, B=8, N=M=8192, 3-D fp32 points — pre-encoded MFMA frags.
// d2 = xx + yy - 2x.y inside mfma_f32_32x32x16_bf16 via split-precision limbs
// packed along K (13/16 slots; absmax 0.0 verified):
//   A row (query q):  [(-2q)h*3, (-2q)l*3, (-2q)h*3, qqh, qql, 1, 1, 0,0,0]
//   B col (target t): [ th*3,     th*3,     tl*3,    1, 1, tth, ttl, 0,0,0]
// R12: R11 showed VGPR_Count=128 -> allocator split 128arch/128agpr and kept
// bouncing accumulators; plus fminf chains never fused to v_min3 (no fast
// math). Fix both: (1) whole hot state engineered to <=128 arch VGPRs
// (depth-2 rotation over THREE f32x16 accs = 48 regs, CT=4, RT=2) so zero
// AGPR copies AND 4 waves/SIMD fit; (2) explicit v_min3_f32 inline asm
// (data finite -> min3 == fmin). grid 1024 = dir(2) x b(8) x cc(64),
// bounds(256,4). Every RED trails its producer MFMA by >=2 MFMA issues +
// prefetch loads (hazard distance ~24-40cyc, R11-proven regime).
// Fin fused via last-block counter. 2 dispatches, no memsets.

#define BB 8
#define NN 8192
#define NPTS (BB*NN)  // 65536
#define BLK 256
#define CCOLS 128     // cols per block
#define CT 4          // col-tiles per block
#define RT 2          // row-tiles per wave per strip
#define STRIPS 32     // 32 strips * 4 waves * 64 rows = 8192
#define GRID 1024     // dir(2) * b(8) * cc(64)

typedef __attribute__((ext_vector_type(8))) short bf16x8;
typedef __attribute__((ext_vector_type(16))) float f32x16;

__device__ __forceinline__ unsigned f2mono(float f) {
    unsigned u = __float_as_uint(f);
    return u ^ ((unsigned)((int)u >> 31) | 0x80000000u);
}
__device__ __forceinline__ float mono2f(unsigned m) {
    unsigned u = ((int)m >= 0) ? ~m : (m ^ 0x80000000u);
    return __uint_as_float(u);
}
__device__ __forceinline__ unsigned bfh(float v) {   // fp32 -> bf16 RNE
    unsigned u = __float_as_uint(v);
    u += 0x7FFFu + ((u >> 16) & 1u);
    return u >> 16;
}
__device__ __forceinline__ float bff(unsigned h) {
    return __uint_as_float(h << 16);
}
__device__ __forceinline__ unsigned pk(unsigned lo, unsigned hi) {
    return (lo & 0xFFFFu) | (hi << 16);
}

// grid 512, block 256: one thread per point (x: [0,NPTS), y: [NPTS,2*NPTS))
__global__ void prep_kernel(const float* __restrict__ x, const float* __restrict__ y,
                            uint4* __restrict__ afr, uint4* __restrict__ bfr,
                            unsigned* __restrict__ counter) {
    int i = blockIdx.x * BLK + threadIdx.x;
    if (i == 0) *counter = 0;
    const float* src = (i < NPTS) ? x : y;
    int j = (i < NPTS) ? i : i - NPTS;
    float c0 = src[3*j], c1 = src[3*j+1], c2 = src[3*j+2];
    float s2 = c0*c0 + c1*c1 + c2*c2;
    unsigned sh = bfh(s2), sl = bfh(s2 - bff(sh));
    float a0 = -2.f*c0, a1 = -2.f*c1, a2 = -2.f*c2;
    unsigned ah0 = bfh(a0), ah1 = bfh(a1), ah2 = bfh(a2);
    unsigned al0 = bfh(a0 - bff(ah0)), al1 = bfh(a1 - bff(ah1)), al2 = bfh(a2 - bff(ah2));
    unsigned bh0 = bfh(c0), bh1 = bfh(c1), bh2 = bfh(c2);
    unsigned bl0 = bfh(c0 - bff(bh0)), bl1 = bfh(c1 - bff(bh1)), bl2 = bfh(c2 - bff(bh2));
    const unsigned one = 0x3F80u;
    afr[2*i]   = make_uint4(pk(ah0,ah1), pk(ah2,al0), pk(al1,al2), pk(ah0,ah1));
    afr[2*i+1] = make_uint4(pk(ah2,sh),  pk(sl,one),  pk(one,0u),  0u);
    bfr[2*i]   = make_uint4(pk(bh0,bh1), pk(bh2,bh0), pk(bh1,bh2), pk(bl0,bl1));
    bfr[2*i+1] = make_uint4(pk(bl2,one), pk(one,sh),  pk(sl,0u),   0u);
}

__device__ __forceinline__ bf16x8 cvt(uint4 v) { return __builtin_bit_cast(bf16x8, v); }

#define SB() __builtin_amdgcn_sched_barrier(0)

// MFMA pinned to arch-VGPR destination (unified file: VGPR C/D legal).
#define MFMA_V(D, A, B)                                                        \
    asm("v_mfma_f32_32x32x16_bf16 %0, %1, %2, %3"                              \
        : "=&v"(D) : "v"(A), "v"(B), "v"(zro))

// Explicit 3-input min (compiler won't fuse fminf chains without fast-math).
#define MIN3(d, a, b, c)                                                       \
    asm("v_min3_f32 %0, %1, %2, %3" : "=v"(d) : "v"(a), "v"(b), "v"(c))

// Reduce one f32x16 accumulator into RM: 8 x v_min3, depth 3.
#define RED16(P, RM) do {                                                      \
    float q0_, q1_, q2_, q3_, q4_, u0_, u1_;                                   \
    MIN3(q0_, P[0],  P[1],  P[2]);                                             \
    MIN3(q1_, P[3],  P[4],  P[5]);                                             \
    MIN3(q2_, P[6],  P[7],  P[8]);                                             \
    MIN3(q3_, P[9],  P[10], P[11]);                                            \
    MIN3(q4_, P[12], P[13], P[14]);                                            \
    MIN3(u0_, q0_, q1_, q2_);                                                  \
    MIN3(u1_, q3_, q4_, P[15]);                                                \
    MIN3(RM, u0_, u1_, RM);                                                    \
} while (0)

// grid: 1024 = (dir<<9) | (b<<6) | cc ; block 256
__global__ __launch_bounds__(BLK, 4) void
main_kernel(const uint4* __restrict__ afr, const uint4* __restrict__ bfr,
            float* __restrict__ bpart, unsigned* __restrict__ counter,
            float* __restrict__ out) {
    __shared__ unsigned colmin[CCOLS];
    __shared__ float red[4];
    __shared__ float gg[8];
    __shared__ int lastflag;
    const int bi  = blockIdx.x;
    const int dir = bi >> 9;
    const int b   = (bi >> 6) & 7;
    const int cc  = bi & 63;
    const uint4* Af = afr + (dir ? 2*NPTS : 0);        // A rows: dir? y : x
    const uint4* Bf = bfr + (dir ? 0 : 2*NPTS);        // B cols: dir? x : y
    const int tid = threadIdx.x;
    const int lane = tid & 63, w = tid >> 6;
    const int m = lane & 31;
    const int hb = lane >> 5;

    if (tid < CCOLS) colmin[tid] = 0xFFFFFFFFu;  // barrier after hot loop

    // this block's 4 B col-tile fragments -> registers (coalesced dwordx4)
    bf16x8 bf[CT];
#pragma unroll
    for (int ct = 0; ct < CT; ++ct) {
        int c = b * NN + cc * CCOLS + ct * 32 + m;
        bf[ct] = cvt(Bf[2*c + hb]);
    }

    f32x16 zro;
#pragma unroll
    for (int i = 0; i < 16; ++i) zro[i] = 0.f;

    float rm[CT];
#pragma unroll
    for (int ct = 0; ct < CT; ++ct) rm[ct] = 3.4e38f;

    // per-thread A base: uint4 index 2*row + hb
    const uint4* Afp = Af + (2 * (b * NN + w * 64 + m) + hb);
    uint4 cur0 = Afp[0], cur1 = Afp[64];

#pragma unroll 1
    for (int s = 0; s < STRIPS; ++s) {
        const int np = (s + 1 < STRIPS) ? (s + 1) : s;   // prefetch next strip
        const bf16x8 A0 = cvt(cur0), A1 = cvt(cur1);

        f32x16 p0, p1, p2;
        MFMA_V(p0, A0, bf[0]);                // k0 -> rm0
        MFMA_V(p1, A1, bf[0]);                // k1 -> rm0
        MFMA_V(p2, A0, bf[1]);                // k2 -> rm1
        // prefetch issue pads the MFMA->VALU hazard distance for p0
        uint4 nxt0 = Afp[np * 512];
        uint4 nxt1 = Afp[np * 512 + 64];
        SB();
        RED16(p0, rm[0]);  MFMA_V(p0, A1, bf[1]);   // k3 -> rm1
        SB();
        RED16(p1, rm[0]);  MFMA_V(p1, A0, bf[2]);   // k4 -> rm2
        SB();
        RED16(p2, rm[1]);  MFMA_V(p2, A1, bf[2]);   // k5 -> rm2
        SB();
        RED16(p0, rm[1]);  MFMA_V(p0, A0, bf[3]);   // k6 -> rm3
        SB();
        RED16(p1, rm[2]);  MFMA_V(p1, A1, bf[3]);   // k7 -> rm3
        SB();
        RED16(p2, rm[2]);
        SB();
        RED16(p0, rm[3]);
        RED16(p1, rm[3]);

        cur0 = nxt0; cur1 = nxt1;
    }

    // merge K-halves in-wave, then across the 4 waves via small LDS atomics
#pragma unroll
    for (int ct = 0; ct < CT; ++ct) {
        float p = fminf(rm[ct], __shfl_xor(rm[ct], 32, 64));
        if (hb == 0) atomicMin(&colmin[ct * 32 + m], f2mono(p));
    }
    __syncthreads();

    // colmin[tid] (tid<128) is the FINAL min-d2 for col (cc*128 + tid)
    float d = (tid < CCOLS) ? sqrtf(fmaxf(mono2f(colmin[tid]), 0.f) + 1e-10f) : 0.f;
#pragma unroll
    for (int off = 32; off; off >>= 1) d += __shfl_down(d, off, 64);
    if (lane == 0) red[w] = d;
    __syncthreads();
    if (tid == 0) {
        float total = red[0] + red[1] + red[2] + red[3];
        atomicExch(&bpart[bi], total);        // device-scope coherent store
        __threadfence();
        unsigned old = atomicAdd(counter, 1u);
        lastflag = (old == (GRID - 1));
    }
    __syncthreads();

    if (lastflag) {                           // block-uniform
        // dir=0 partials: bpart[0..511]; dir=1: bpart[512..1023]
        float v0 = atomicAdd(&bpart[2*tid], 0.f) + atomicAdd(&bpart[2*tid+1], 0.f);
        float v1 = atomicAdd(&bpart[512 + 2*tid], 0.f) + atomicAdd(&bpart[512 + 2*tid+1], 0.f);
#pragma unroll
        for (int off = 16; off; off >>= 1) {
            v0 += __shfl_down(v0, off, 32);
            v1 += __shfl_down(v1, off, 32);
        }
        if ((tid & 31) == 0) gg[tid >> 5] = fmaxf(v0, v1);
        __syncthreads();
        if (tid == 0) {
            float acc = 0.f;
#pragma unroll
            for (int k = 0; k < 8; ++k) acc += gg[k];
            out[0] = acc * (1.0f / (float)NN);
        }
    }
}

extern "C" void kernel_launch(void* const* d_in, const int* in_sizes, int n_in,
                              void* d_out, int out_size, void* d_ws, size_t ws_size,
                              hipStream_t stream) {
    const float* x = (const float*)d_in[0];
    const float* y = (const float*)d_in[1];
    float* out = (float*)d_out;

    char* ws = (char*)d_ws;
    uint4* afr = (uint4*)ws;                     // 2*NPTS*2 uint4 = 4 MB
    uint4* bfr = afr + 4 * NPTS;                 // 4 MB
    float* bpart = (float*)(bfr + 4 * NPTS);     // 1024 floats
    unsigned* counter = (unsigned*)(bpart + GRID);

    prep_kernel<<<(2 * NPTS) / BLK, BLK, 0, stream>>>(x, y, afr, bfr, counter);
    main_kernel<<<GRID, BLK, 0, stream>>>(afr, bfr, bpart, counter, out);
}

// Round 6
// 98.869 us; speedup vs baseline: 1.1321x; 1.1321x over previous
//
#include <hip/hip_runtime.h>

// Chamfer distance, B=8, N=M=8192, 3-D fp32 points — pre-encoded MFMA frags.
// d2 = xx + yy - 2x.y inside mfma_f32_32x32x16_bf16 via split-precision limbs
// packed along K (13/16 slots; absmax 0.0 verified):
//   A row (query q):  [(-2q)h*3, (-2q)l*3, (-2q)h*3, qqh, qql, 1, 1, 0,0,0]
//   B col (target t): [ th*3,     th*3,     tl*3,    1, 1, tth, ttl, 0,0,0]
// R13: model refined — kernel is VALU-ISSUE-bound on the min reduction:
// 41k VALU cyc/SIMD ~= 20.5k unfused fminf (compiler won't form v_min3
// without fast-math) + 16k accvgpr copies. R12 re-confirmed 4-blocks/CU
// always loses (55 vs 44us) — that axis is dead. This round: keep R11
// exactly (asm MFMA "=&v" -> accs in arch VGPRs, 2 blocks/CU, depth-2
// pinned pipeline) and replace RED4's ~80 v_min chain with an explicit
// v_min3_f32 tree: 64 vals + rm -> 21+7+3+1 = 32 min3, depth 4, zero
// accvgpr traffic on the reduction path (min3 reads asm VGPR outputs
// directly). min3==fmin here: all values finite.
// Geometry: grid 512 / CT=8 / RT=4 / bounds(256,2).
// Fin fused via last-block counter. 2 dispatches, no memsets.

#define BB 8
#define NN 8192
#define NPTS (BB*NN)  // 65536
#define BLK 256
#define CCOLS 256
#define CT 8          // col-tiles per block
#define RT 4          // row-tiles per strip per wave
#define STRIPS 16     // 16 strips * 4 waves * 128 rows = 8192

typedef __attribute__((ext_vector_type(8))) short bf16x8;
typedef __attribute__((ext_vector_type(16))) float f32x16;

__device__ __forceinline__ unsigned f2mono(float f) {
    unsigned u = __float_as_uint(f);
    return u ^ ((unsigned)((int)u >> 31) | 0x80000000u);
}
__device__ __forceinline__ float mono2f(unsigned m) {
    unsigned u = ((int)m >= 0) ? ~m : (m ^ 0x80000000u);
    return __uint_as_float(u);
}
__device__ __forceinline__ unsigned bfh(float v) {   // fp32 -> bf16 RNE
    unsigned u = __float_as_uint(v);
    u += 0x7FFFu + ((u >> 16) & 1u);
    return u >> 16;
}
__device__ __forceinline__ float bff(unsigned h) {
    return __uint_as_float(h << 16);
}
__device__ __forceinline__ unsigned pk(unsigned lo, unsigned hi) {
    return (lo & 0xFFFFu) | (hi << 16);
}

// grid 512, block 256: one thread per point (x: [0,NPTS), y: [NPTS,2*NPTS))
__global__ void prep_kernel(const float* __restrict__ x, const float* __restrict__ y,
                            uint4* __restrict__ afr, uint4* __restrict__ bfr,
                            unsigned* __restrict__ counter) {
    int i = blockIdx.x * BLK + threadIdx.x;
    if (i == 0) *counter = 0;
    const float* src = (i < NPTS) ? x : y;
    int j = (i < NPTS) ? i : i - NPTS;
    float c0 = src[3*j], c1 = src[3*j+1], c2 = src[3*j+2];
    float s2 = c0*c0 + c1*c1 + c2*c2;
    unsigned sh = bfh(s2), sl = bfh(s2 - bff(sh));
    float a0 = -2.f*c0, a1 = -2.f*c1, a2 = -2.f*c2;
    unsigned ah0 = bfh(a0), ah1 = bfh(a1), ah2 = bfh(a2);
    unsigned al0 = bfh(a0 - bff(ah0)), al1 = bfh(a1 - bff(ah1)), al2 = bfh(a2 - bff(ah2));
    unsigned bh0 = bfh(c0), bh1 = bfh(c1), bh2 = bfh(c2);
    unsigned bl0 = bfh(c0 - bff(bh0)), bl1 = bfh(c1 - bff(bh1)), bl2 = bfh(c2 - bff(bh2));
    const unsigned one = 0x3F80u;
    afr[2*i]   = make_uint4(pk(ah0,ah1), pk(ah2,al0), pk(al1,al2), pk(ah0,ah1));
    afr[2*i+1] = make_uint4(pk(ah2,sh),  pk(sl,one),  pk(one,0u),  0u);
    bfr[2*i]   = make_uint4(pk(bh0,bh1), pk(bh2,bh0), pk(bh1,bh2), pk(bl0,bl1));
    bfr[2*i+1] = make_uint4(pk(bl2,one), pk(one,sh),  pk(sl,0u),   0u);
}

__device__ __forceinline__ bf16x8 cvt(uint4 v) { return __builtin_bit_cast(bf16x8, v); }

#define SB() __builtin_amdgcn_sched_barrier(0)

// MFMA pinned to arch-VGPR destination (unified file: VGPR C/D legal).
#define MFMA_V(D, A, B)                                                        \
    asm("v_mfma_f32_32x32x16_bf16 %0, %1, %2, %3"                              \
        : "=&v"(D) : "v"(A), "v"(B), "v"(zro))

// Explicit 3-input min (compiler won't fuse fminf chains without fast-math).
#define MIN3(d, a, b, c)                                                       \
    asm("v_min3_f32 %0, %1, %2, %3" : "=v"(d) : "v"(a), "v"(b), "v"(c))

// Issue 4 row-tile MFMAs for one B col-tile into a named accumulator set.
#define ISSUE4(B, R0, R1, R2, R3)                                              \
    MFMA_V(R0, ca0, (B));                                                      \
    MFMA_V(R1, ca1, (B));                                                      \
    MFMA_V(R2, ca2, (B));                                                      \
    MFMA_V(R3, ca3, (B));

// Reduce a 4-accumulator set (64 f32) + RM via a 32-op v_min3 tree, depth 4.
#define RED4(P0, P1, P2, P3, RM) do {                                          \
    float g0_, g1_, g2_, g3_, g4_, g5_, g6_, g7_, g8_, g9_, g10_,              \
          g11_, g12_, g13_, g14_, g15_, g16_, g17_, g18_, g19_, g20_;          \
    float h0_, h1_, h2_, h3_, h4_, h5_, h6_;                                   \
    float u0_, u1_, u2_;                                                       \
    MIN3(g0_,  P0[0],  P0[1],  P0[2]);                                         \
    MIN3(g1_,  P0[3],  P0[4],  P0[5]);                                         \
    MIN3(g2_,  P0[6],  P0[7],  P0[8]);                                         \
    MIN3(g3_,  P0[9],  P0[10], P0[11]);                                        \
    MIN3(g4_,  P0[12], P0[13], P0[14]);                                        \
    MIN3(g5_,  P0[15], P1[0],  P1[1]);                                         \
    MIN3(g6_,  P1[2],  P1[3],  P1[4]);                                         \
    MIN3(g7_,  P1[5],  P1[6],  P1[7]);                                         \
    MIN3(g8_,  P1[8],  P1[9],  P1[10]);                                        \
    MIN3(g9_,  P1[11], P1[12], P1[13]);                                        \
    MIN3(g10_, P1[14], P1[15], P2[0]);                                         \
    MIN3(g11_, P2[1],  P2[2],  P2[3]);                                         \
    MIN3(g12_, P2[4],  P2[5],  P2[6]);                                         \
    MIN3(g13_, P2[7],  P2[8],  P2[9]);                                         \
    MIN3(g14_, P2[10], P2[11], P2[12]);                                        \
    MIN3(g15_, P2[13], P2[14], P2[15]);                                        \
    MIN3(g16_, P3[0],  P3[1],  P3[2]);                                         \
    MIN3(g17_, P3[3],  P3[4],  P3[5]);                                         \
    MIN3(g18_, P3[6],  P3[7],  P3[8]);                                         \
    MIN3(g19_, P3[9],  P3[10], P3[11]);                                        \
    MIN3(g20_, P3[12], P3[13], P3[14]);                                        \
    MIN3(h0_, g0_,  g1_,  g2_);                                                \
    MIN3(h1_, g3_,  g4_,  g5_);                                                \
    MIN3(h2_, g6_,  g7_,  g8_);                                                \
    MIN3(h3_, g9_,  g10_, g11_);                                               \
    MIN3(h4_, g12_, g13_, g14_);                                               \
    MIN3(h5_, g15_, g16_, g17_);                                               \
    MIN3(h6_, g18_, g19_, g20_);                                               \
    MIN3(u0_, h0_, h1_, h2_);                                                  \
    MIN3(u1_, h3_, h4_, h5_);                                                  \
    MIN3(u2_, h6_, P3[15], (RM));                                              \
    MIN3((RM), u0_, u1_, u2_);                                                 \
} while (0)

// grid: 512 = (dir<<8) | (b<<5) | cc ; block 256
__global__ __launch_bounds__(BLK, 2) void
main_kernel(const uint4* __restrict__ afr, const uint4* __restrict__ bfr,
            float* __restrict__ bpart, unsigned* __restrict__ counter,
            float* __restrict__ out) {
    __shared__ unsigned colmin[CCOLS];
    __shared__ float red[4];
    __shared__ float gg[8];
    __shared__ int lastflag;
    const int bi  = blockIdx.x;
    const int dir = bi >> 8;
    const int b   = (bi >> 5) & 7;
    const int cc  = bi & 31;
    const uint4* Af = afr + (dir ? 2*NPTS : 0);        // A rows: dir? y : x
    const uint4* Bf = bfr + (dir ? 0 : 2*NPTS);        // B cols: dir? x : y
    const int tid = threadIdx.x;
    const int lane = tid & 63, w = tid >> 6;
    const int m = lane & 31;
    const int hb = lane >> 5;

    colmin[tid] = 0xFFFFFFFFu;       // barrier comes after the hot loop

    // this block's 8 B col-tile fragments -> registers (coalesced dwordx4)
    bf16x8 bf[CT];
#pragma unroll
    for (int ct = 0; ct < CT; ++ct) {
        int c = b * NN + cc * CCOLS + ct * 32 + m;
        bf[ct] = cvt(Bf[2*c + hb]);
    }

    f32x16 zro;
#pragma unroll
    for (int i = 0; i < 16; ++i) zro[i] = 0.f;

    float rm[CT];
#pragma unroll
    for (int ct = 0; ct < CT; ++ct) rm[ct] = 3.4e38f;

    const int rowbase = b * NN + w * 128 + m;
    uint4 cur[RT], nxt[RT];
#pragma unroll
    for (int t = 0; t < RT; ++t) cur[t] = Af[2*(rowbase + t*32) + hb];

#pragma unroll 1
    for (int s = 0; s < STRIPS; ++s) {
        const int np = (s + 1 < STRIPS) ? (s + 1) : s;   // prefetch next strip
#pragma unroll
        for (int t = 0; t < RT; ++t) nxt[t] = Af[2*(rowbase + np*512 + t*32) + hb];

        const bf16x8 ca0 = cvt(cur[0]), ca1 = cvt(cur[1]);
        const bf16x8 ca2 = cvt(cur[2]), ca3 = cvt(cur[3]);

        // Depth-2 software pipeline, PINNED with sched_barrier(0): while set
        // X is min3-reduced on the VALU, set Y's 4 MFMAs run in the matrix
        // pipe. Accumulators in arch VGPRs via the asm "=&v" constraint.
        f32x16 e0, e1, e2, e3, o0, o1, o2, o3;
        ISSUE4(bf[0], e0, e1, e2, e3);
        ISSUE4(bf[1], o0, o1, o2, o3);
        SB();
        RED4(e0, e1, e2, e3, rm[0]);  ISSUE4(bf[2], e0, e1, e2, e3);
        SB();
        RED4(o0, o1, o2, o3, rm[1]);  ISSUE4(bf[3], o0, o1, o2, o3);
        SB();
        RED4(e0, e1, e2, e3, rm[2]);  ISSUE4(bf[4], e0, e1, e2, e3);
        SB();
        RED4(o0, o1, o2, o3, rm[3]);  ISSUE4(bf[5], o0, o1, o2, o3);
        SB();
        RED4(e0, e1, e2, e3, rm[4]);  ISSUE4(bf[6], e0, e1, e2, e3);
        SB();
        RED4(o0, o1, o2, o3, rm[5]);  ISSUE4(bf[7], o0, o1, o2, o3);
        SB();
        RED4(e0, e1, e2, e3, rm[6]);
        RED4(o0, o1, o2, o3, rm[7]);

#pragma unroll
        for (int t = 0; t < RT; ++t) cur[t] = nxt[t];
    }

    // merge K-halves in-wave, then across the 4 waves via small LDS atomics
#pragma unroll
    for (int ct = 0; ct < CT; ++ct) {
        float p = fminf(rm[ct], __shfl_xor(rm[ct], 32, 64));
        if (hb == 0) atomicMin(&colmin[ct * 32 + m], f2mono(p));
    }
    __syncthreads();

    // colmin[tid] is the FINAL min-d2 for col (cc*256 + tid)
    float d = sqrtf(fmaxf(mono2f(colmin[tid]), 0.f) + 1e-10f);
#pragma unroll
    for (int off = 32; off; off >>= 1) d += __shfl_down(d, off, 64);
    if (lane == 0) red[w] = d;
    __syncthreads();
    if (tid == 0) {
        float total = red[0] + red[1] + red[2] + red[3];
        atomicExch(&bpart[bi], total);        // device-scope coherent store
        __threadfence();
        unsigned old = atomicAdd(counter, 1u);
        lastflag = (old == 511u);
    }
    __syncthreads();

    if (lastflag) {                           // block-uniform
        float v0 = atomicAdd(&bpart[tid], 0.f);        // dir=0, group=tid>>5
        float v1 = atomicAdd(&bpart[256 + tid], 0.f);  // dir=1
#pragma unroll
        for (int off = 16; off; off >>= 1) {
            v0 += __shfl_down(v0, off, 32);
            v1 += __shfl_down(v1, off, 32);
        }
        if ((tid & 31) == 0) gg[tid >> 5] = fmaxf(v0, v1);
        __syncthreads();
        if (tid == 0) {
            float acc = 0.f;
#pragma unroll
            for (int k = 0; k < 8; ++k) acc += gg[k];
            out[0] = acc * (1.0f / (float)NN);
        }
    }
}

extern "C" void kernel_launch(void* const* d_in, const int* in_sizes, int n_in,
                              void* d_out, int out_size, void* d_ws, size_t ws_size,
                              hipStream_t stream) {
    const float* x = (const float*)d_in[0];
    const float* y = (const float*)d_in[1];
    float* out = (float*)d_out;

    char* ws = (char*)d_ws;
    uint4* afr = (uint4*)ws;                     // 2*NPTS*2 uint4 = 4 MB
    uint4* bfr = afr + 4 * NPTS;                 // 4 MB
    float* bpart = (float*)(bfr + 4 * NPTS);     // 512 floats
    unsigned* counter = (unsigned*)(bpart + 512);

    prep_kernel<<<(2 * NPTS) / BLK, BLK, 0, stream>>>(x, y, afr, bfr, counter);
    main_kernel<<<512, BLK, 0, stream>>>(afr, bfr, bpart, counter, out);
}

// Round 8
// 97.881 us; speedup vs baseline: 1.1435x; 1.0101x over previous
//
#include <hip/hip_runtime.h>

// Chamfer distance, B=8, N=M=8192, 3-D fp32 points — pre-encoded MFMA frags.
// d2 = xx + yy - 2x.y inside mfma_f32_32x32x16_bf16 via split-precision limbs
// packed along K (13/16 slots; absmax 0.0 verified):
//   A row (query q):  [(-2q)h*3, (-2q)l*3, (-2q)h*3, qqh, qql, 1, 1, 0,0,0]
//   B col (target t): [ th*3,     th*3,     tl*3,    1, 1, tth, ttl, 0,0,0]
// R15 == R14 resubmitted verbatim: previous round died on container
// acquisition (no compile/correctness/counter signal). Hypothesis under
// test unchanged: main stuck at ~43us across R9-R13 because ~230 live
// values make the allocator split the unified file 128v+128a and surround
// every MFMA with copy traffic. Fix: shrink live state to ~150 so the
// whole kernel fits arch VGPRs with NO AGPR split: RT 4->2, STRIPS 16->32
// (same total work), depth-2 pipeline over 2-acc sets, 16-op min3 tree per
// RED2. Verification signal: VGPR_Count ~145-175 (pure) vs 128 (split).
// Geometry: grid 512 / CCOLS=256 / CT=8 / bounds(256,2).
// Fin fused via last-block counter. 2 dispatches, no memsets.

#define BB 8
#define NN 8192
#define NPTS (BB*NN)  // 65536
#define BLK 256
#define CCOLS 256
#define CT 8          // col-tiles per block
#define RT 2          // row-tiles per strip per wave
#define STRIPS 32     // 32 strips * 4 waves * 64 rows = 8192

typedef __attribute__((ext_vector_type(8))) short bf16x8;
typedef __attribute__((ext_vector_type(16))) float f32x16;

__device__ __forceinline__ unsigned f2mono(float f) {
    unsigned u = __float_as_uint(f);
    return u ^ ((unsigned)((int)u >> 31) | 0x80000000u);
}
__device__ __forceinline__ float mono2f(unsigned m) {
    unsigned u = ((int)m >= 0) ? ~m : (m ^ 0x80000000u);
    return __uint_as_float(u);
}
__device__ __forceinline__ unsigned bfh(float v) {   // fp32 -> bf16 RNE
    unsigned u = __float_as_uint(v);
    u += 0x7FFFu + ((u >> 16) & 1u);
    return u >> 16;
}
__device__ __forceinline__ float bff(unsigned h) {
    return __uint_as_float(h << 16);
}
__device__ __forceinline__ unsigned pk(unsigned lo, unsigned hi) {
    return (lo & 0xFFFFu) | (hi << 16);
}

// grid 512, block 256: one thread per point (x: [0,NPTS), y: [NPTS,2*NPTS))
__global__ void prep_kernel(const float* __restrict__ x, const float* __restrict__ y,
                            uint4* __restrict__ afr, uint4* __restrict__ bfr,
                            unsigned* __restrict__ counter) {
    int i = blockIdx.x * BLK + threadIdx.x;
    if (i == 0) *counter = 0;
    const float* src = (i < NPTS) ? x : y;
    int j = (i < NPTS) ? i : i - NPTS;
    float c0 = src[3*j], c1 = src[3*j+1], c2 = src[3*j+2];
    float s2 = c0*c0 + c1*c1 + c2*c2;
    unsigned sh = bfh(s2), sl = bfh(s2 - bff(sh));
    float a0 = -2.f*c0, a1 = -2.f*c1, a2 = -2.f*c2;
    unsigned ah0 = bfh(a0), ah1 = bfh(a1), ah2 = bfh(a2);
    unsigned al0 = bfh(a0 - bff(ah0)), al1 = bfh(a1 - bff(ah1)), al2 = bfh(a2 - bff(ah2));
    unsigned bh0 = bfh(c0), bh1 = bfh(c1), bh2 = bfh(c2);
    unsigned bl0 = bfh(c0 - bff(bh0)), bl1 = bfh(c1 - bff(bh1)), bl2 = bfh(c2 - bff(bh2));
    const unsigned one = 0x3F80u;
    afr[2*i]   = make_uint4(pk(ah0,ah1), pk(ah2,al0), pk(al1,al2), pk(ah0,ah1));
    afr[2*i+1] = make_uint4(pk(ah2,sh),  pk(sl,one),  pk(one,0u),  0u);
    bfr[2*i]   = make_uint4(pk(bh0,bh1), pk(bh2,bh0), pk(bh1,bh2), pk(bl0,bl1));
    bfr[2*i+1] = make_uint4(pk(bl2,one), pk(one,sh),  pk(sl,0u),   0u);
}

__device__ __forceinline__ bf16x8 cvt(uint4 v) { return __builtin_bit_cast(bf16x8, v); }

#define SB() __builtin_amdgcn_sched_barrier(0)

// MFMA pinned to arch-VGPR destination (unified file: VGPR C/D legal).
#define MFMA_V(D, A, B)                                                        \
    asm("v_mfma_f32_32x32x16_bf16 %0, %1, %2, %3"                              \
        : "=&v"(D) : "v"(A), "v"(B), "v"(zro))

// Explicit 3-input min (compiler won't fuse fminf chains without fast-math).
#define MIN3(d, a, b, c)                                                       \
    asm("v_min3_f32 %0, %1, %2, %3" : "=v"(d) : "v"(a), "v"(b), "v"(c))

// Issue 2 row-tile MFMAs for one B col-tile into a named accumulator set.
#define ISSUE2(B, R0, R1)                                                      \
    MFMA_V(R0, ca0, (B));                                                      \
    MFMA_V(R1, ca1, (B));

// Reduce a 2-accumulator set (32 f32) + RM via a 16-op v_min3 tree, depth 4.
#define RED2(P0, P1, RM) do {                                                  \
    float g0_, g1_, g2_, g3_, g4_, g5_, g6_, g7_, g8_, g9_, g10_;              \
    float h0_, h1_, h2_, u0_;                                                  \
    MIN3(g0_,  P0[0],  P0[1],  P0[2]);                                         \
    MIN3(g1_,  P0[3],  P0[4],  P0[5]);                                         \
    MIN3(g2_,  P0[6],  P0[7],  P0[8]);                                         \
    MIN3(g3_,  P0[9],  P0[10], P0[11]);                                        \
    MIN3(g4_,  P0[12], P0[13], P0[14]);                                        \
    MIN3(g5_,  P0[15], P1[0],  P1[1]);                                         \
    MIN3(g6_,  P1[2],  P1[3],  P1[4]);                                         \
    MIN3(g7_,  P1[5],  P1[6],  P1[7]);                                         \
    MIN3(g8_,  P1[8],  P1[9],  P1[10]);                                        \
    MIN3(g9_,  P1[11], P1[12], P1[13]);                                        \
    MIN3(g10_, P1[14], P1[15], (RM));                                          \
    MIN3(h0_, g0_, g1_, g2_);                                                  \
    MIN3(h1_, g3_, g4_, g5_);                                                  \
    MIN3(h2_, g6_, g7_, g8_);                                                  \
    MIN3(u0_, h0_, h1_, h2_);                                                  \
    MIN3((RM), u0_, g9_, g10_);                                                \
} while (0)

// grid: 512 = (dir<<8) | (b<<5) | cc ; block 256
__global__ __launch_bounds__(BLK, 2) void
main_kernel(const uint4* __restrict__ afr, const uint4* __restrict__ bfr,
            float* __restrict__ bpart, unsigned* __restrict__ counter,
            float* __restrict__ out) {
    __shared__ unsigned colmin[CCOLS];
    __shared__ float red[4];
    __shared__ float gg[8];
    __shared__ int lastflag;
    const int bi  = blockIdx.x;
    const int dir = bi >> 8;
    const int b   = (bi >> 5) & 7;
    const int cc  = bi & 31;
    const uint4* Af = afr + (dir ? 2*NPTS : 0);        // A rows: dir? y : x
    const uint4* Bf = bfr + (dir ? 0 : 2*NPTS);        // B cols: dir? x : y
    const int tid = threadIdx.x;
    const int lane = tid & 63, w = tid >> 6;
    const int m = lane & 31;
    const int hb = lane >> 5;

    colmin[tid] = 0xFFFFFFFFu;       // barrier comes after the hot loop

    // this block's 8 B col-tile fragments -> registers (coalesced dwordx4)
    bf16x8 bf[CT];
#pragma unroll
    for (int ct = 0; ct < CT; ++ct) {
        int c = b * NN + cc * CCOLS + ct * 32 + m;
        bf[ct] = cvt(Bf[2*c + hb]);
    }

    f32x16 zro;
#pragma unroll
    for (int i = 0; i < 16; ++i) zro[i] = 0.f;

    float rm[CT];
#pragma unroll
    for (int ct = 0; ct < CT; ++ct) rm[ct] = 3.4e38f;

    // per strip: 4 waves x RT(2) x 32 = 256 rows; 32 strips cover 8192.
    const int rowbase = b * NN + w * 64 + m;
    uint4 cur[RT], nxt[RT];
#pragma unroll
    for (int t = 0; t < RT; ++t) cur[t] = Af[2*(rowbase + t*32) + hb];

#pragma unroll 1
    for (int s = 0; s < STRIPS; ++s) {
        const int np = (s + 1 < STRIPS) ? (s + 1) : s;   // prefetch next strip
#pragma unroll
        for (int t = 0; t < RT; ++t) nxt[t] = Af[2*(rowbase + np*256 + t*32) + hb];

        const bf16x8 ca0 = cvt(cur[0]), ca1 = cvt(cur[1]);

        // Depth-2 software pipeline, PINNED with sched_barrier(0): while set
        // X is min3-reduced on the VALU, set Y's 2 MFMAs run in the matrix
        // pipe. Total live state ~150 regs -> expect pure-VGPR allocation.
        f32x16 e0, e1, o0, o1;
        ISSUE2(bf[0], e0, e1);
        ISSUE2(bf[1], o0, o1);
        SB();
        RED2(e0, e1, rm[0]);  ISSUE2(bf[2], e0, e1);
        SB();
        RED2(o0, o1, rm[1]);  ISSUE2(bf[3], o0, o1);
        SB();
        RED2(e0, e1, rm[2]);  ISSUE2(bf[4], e0, e1);
        SB();
        RED2(o0, o1, rm[3]);  ISSUE2(bf[5], o0, o1);
        SB();
        RED2(e0, e1, rm[4]);  ISSUE2(bf[6], e0, e1);
        SB();
        RED2(o0, o1, rm[5]);  ISSUE2(bf[7], o0, o1);
        SB();
        RED2(e0, e1, rm[6]);
        RED2(o0, o1, rm[7]);

#pragma unroll
        for (int t = 0; t < RT; ++t) cur[t] = nxt[t];
    }

    // merge K-halves in-wave, then across the 4 waves via small LDS atomics
#pragma unroll
    for (int ct = 0; ct < CT; ++ct) {
        float p = fminf(rm[ct], __shfl_xor(rm[ct], 32, 64));
        if (hb == 0) atomicMin(&colmin[ct * 32 + m], f2mono(p));
    }
    __syncthreads();

    // colmin[tid] is the FINAL min-d2 for col (cc*256 + tid)
    float d = sqrtf(fmaxf(mono2f(colmin[tid]), 0.f) + 1e-10f);
#pragma unroll
    for (int off = 32; off; off >>= 1) d += __shfl_down(d, off, 64);
    if (lane == 0) red[w] = d;
    __syncthreads();
    if (tid == 0) {
        float total = red[0] + red[1] + red[2] + red[3];
        atomicExch(&bpart[bi], total);        // device-scope coherent store
        __threadfence();
        unsigned old = atomicAdd(counter, 1u);
        lastflag = (old == 511u);
    }
    __syncthreads();

    if (lastflag) {                           // block-uniform
        float v0 = atomicAdd(&bpart[tid], 0.f);        // dir=0, group=tid>>5
        float v1 = atomicAdd(&bpart[256 + tid], 0.f);  // dir=1
#pragma unroll
        for (int off = 16; off; off >>= 1) {
            v0 += __shfl_down(v0, off, 32);
            v1 += __shfl_down(v1, off, 32);
        }
        if ((tid & 31) == 0) gg[tid >> 5] = fmaxf(v0, v1);
        __syncthreads();
        if (tid == 0) {
            float acc = 0.f;
#pragma unroll
            for (int k = 0; k < 8; ++k) acc += gg[k];
            out[0] = acc * (1.0f / (float)NN);
        }
    }
}

extern "C" void kernel_launch(void* const* d_in, const int* in_sizes, int n_in,
                              void* d_out, int out_size, void* d_ws, size_t ws_size,
                              hipStream_t stream) {
    const float* x = (const float*)d_in[0];
    const float* y = (const float*)d_in[1];
    float* out = (float*)d_out;

    char* ws = (char*)d_ws;
    uint4* afr = (uint4*)ws;                     // 2*NPTS*2 uint4 = 4 MB
    uint4* bfr = afr + 4 * NPTS;                 // 4 MB
    float* bpart = (float*)(bfr + 4 * NPTS);     // 512 floats
    unsigned* counter = (unsigned*)(bpart + 512);

    prep_kernel<<<(2 * NPTS) / BLK, BLK, 0, stream>>>(x, y, afr, bfr, counter);
    main_kernel<<<512, BLK, 0, stream>>>(afr, bfr, bpart, counter, out);
}